// Round 1
// baseline (126.652 us; speedup 1.0000x reference)
//
#include <hip/hip_runtime.h>
#include <math.h>

#define B_ 2
#define T_ 4096
#define N_ 128
#define L_ 64

constexpr float GAMMA_ = 0.75f;
constexpr float EPS_ = 1e-6f;

// ---------------------------------------------------------------------------
// K1: elementwise transform.  For each (b,t,n) element x of preds_mask:
//   p   = sigmoid(x)
//   spn = softplus(-x),  spp = softplus(x) = x + spn
//   A   = (1-p+eps)^0.25 * spn      (focal term when target==1)
//   Bv  = (p+eps)^0.25   * spp      (focal term when target==0)
// Store float4(p, A-Bv, Bv, 0) at transposed position [b][n][t] so K2 can
// read rows contiguously.
// ---------------------------------------------------------------------------
__global__ void k_transform(const float* __restrict__ preds, float4* __restrict__ pdb) {
    int idx = blockIdx.x * blockDim.x + threadIdx.x;
    if (idx >= B_ * T_ * N_) return;
    int b = idx / (T_ * N_);
    int r = idx - b * (T_ * N_);
    int t = r >> 7;          // / N_
    int n = r & (N_ - 1);

    float x = preds[idx];
    float e = expf(-x);
    float p = 1.0f / (1.0f + e);
    float spn = logf(1.0f + e);   // softplus(-x)
    float spp = x + spn;          // softplus(x)
    float A  = sqrtf(sqrtf(1.0f - p + EPS_)) * spn;   // ^0.25
    float Bv = sqrtf(sqrtf(p + EPS_)) * spp;

    pdb[(b * N_ + n) * T_ + t] = make_float4(p, A - Bv, Bv, 0.0f);
}

// ---------------------------------------------------------------------------
// K2: per (b,n) row: two matvecs against targets plus row sums.
//   TP[n,m] = sum_t p[n,t] * tgt[t,m]
//   DD[n,m] = sum_t (A-B)[n,t] * tgt[t,m]
//   sumP[n] = sum_t p[n,t],  sumB[n] = sum_t Bv[n,t]
// 1024 threads: m = tid&63 (coalesced tgt reads), q = tid>>6 gives 16 t-slices
// of 256 each.  Row loads are wave-uniform (scalarize to s_load).
// ---------------------------------------------------------------------------
__global__ void __launch_bounds__(1024)
k_matmul(const float4* __restrict__ pdb, const float* __restrict__ targets,
         float* __restrict__ TP, float* __restrict__ DD,
         float* __restrict__ sumP, float* __restrict__ sumB) {
    int bn = blockIdx.x;              // 0..B_*N_-1
    int b  = bn >> 7;                 // / N_
    int tid = threadIdx.x;
    int m = tid & 63;
    int q = tid >> 6;                 // 0..15

    const float4* row = pdb + (size_t)bn * T_;
    const float* tg = targets + (size_t)b * T_ * L_;

    float tp = 0.0f, dd = 0.0f, sp = 0.0f, sb = 0.0f;
    const int TS = T_ / 16;           // 256
    int t0 = q * TS;
#pragma unroll 4
    for (int t = t0; t < t0 + TS; ++t) {
        float4 v = row[t];
        float g = tg[t * L_ + m];
        tp = fmaf(v.x, g, tp);
        dd = fmaf(v.y, g, dd);
        sp += v.x;
        sb += v.z;
    }

    __shared__ float rtp[16][64];
    __shared__ float rdd[16][64];
    __shared__ float rsp[16];
    __shared__ float rsb[16];
    rtp[q][m] = tp;
    rdd[q][m] = dd;
    if (m == 0) { rsp[q] = sp; rsb[q] = sb; }
    __syncthreads();

    if (q == 0) {
        float a = 0.0f, c = 0.0f;
#pragma unroll
        for (int k = 0; k < 16; ++k) { a += rtp[k][m]; c += rdd[k][m]; }
        TP[bn * L_ + m] = a;
        DD[bn * L_ + m] = c;
        if (m == 0) {
            float s1 = 0.0f, s2 = 0.0f;
#pragma unroll
            for (int k = 0; k < 16; ++k) { s1 += rsp[k]; s2 += rsb[k]; }
            sumP[bn] = s1;
            sumB[bn] = s2;
        }
    }
}

// ---------------------------------------------------------------------------
// K3: finalize.  One block per (b,m); 128 threads, one per n.
//   sumT[b,m] = sum_t tgt[t,m]  (block reduce)
//   wsum      = sum_{j<L} weight[j]
//   cost_dia  = (weight[m]/wsum) * (sumB[n] + DD[n,m]) / T
//   tversky   = (tp+eps)/(tp + a*fp + b*fn + eps); cost_dice = (1-tv+eps)^0.75
//   out       = 5*dia + 5*dice - 2*sigmoid(cls[n])
// ---------------------------------------------------------------------------
__global__ void k_final(const float* __restrict__ targets, const float* __restrict__ preds_class,
                        const float* __restrict__ weight, const float* __restrict__ alpha,
                        const float* __restrict__ beta,
                        const float* __restrict__ TP, const float* __restrict__ DD,
                        const float* __restrict__ sumP, const float* __restrict__ sumB,
                        float* __restrict__ out) {
    int bm = blockIdx.x;              // 0..B_*L_-1
    int b = bm >> 6;                  // / L_
    int m = bm & 63;
    int tid = threadIdx.x;            // 0..127 (= n)

    __shared__ float sd[128];

    // sumT[b,m]
    const float* tg = targets + (size_t)b * T_ * L_;
    float s = 0.0f;
    for (int t = tid; t < T_; t += 128) s += tg[t * L_ + m];
    sd[tid] = s;
    __syncthreads();
    for (int w = 64; w > 0; w >>= 1) {
        if (tid < w) sd[tid] += sd[tid + w];
        __syncthreads();
    }
    float sumTv = sd[0];
    __syncthreads();

    // wsum = sum of weight[:L]
    sd[tid] = (tid < L_) ? weight[tid] : 0.0f;
    __syncthreads();
    for (int w = 64; w > 0; w >>= 1) {
        if (tid < w) sd[tid] += sd[tid + w];
        __syncthreads();
    }
    float wsum = sd[0];

    int bn = b * N_ + tid;
    float tp = TP[bn * L_ + m];
    float dd = DD[bn * L_ + m];
    float sp = sumP[bn];
    float sb = sumB[bn];
    float a  = alpha[m];
    float bb = beta[m];

    float cost_dia = (weight[m] / wsum) * (sb + dd) * (1.0f / (float)T_);

    float fpv = sp - tp;
    float fnv = sumTv - tp;
    float tv = (tp + EPS_) / (tp + a * fpv + bb * fnv + EPS_);
    float cost_dice = powf(1.0f - tv + EPS_, GAMMA_);

    float cls = preds_class[bn];
    float sig = 1.0f / (1.0f + expf(-cls));

    out[bn * L_ + m] = 5.0f * cost_dia + 5.0f * cost_dice - 2.0f * sig;
}

extern "C" void kernel_launch(void* const* d_in, const int* in_sizes, int n_in,
                              void* d_out, int out_size, void* d_ws, size_t ws_size,
                              hipStream_t stream) {
    const float* preds_mask  = (const float*)d_in[0];   // (B,T,N)
    const float* preds_class = (const float*)d_in[1];   // (B,N,1)
    const float* targets     = (const float*)d_in[2];   // (B,T,L)
    const float* weight      = (const float*)d_in[3];   // (N,)
    const float* alpha       = (const float*)d_in[4];   // (N,)
    const float* beta        = (const float*)d_in[5];   // (N,)
    float* out = (float*)d_out;

    // workspace layout
    float4* pdb = (float4*)d_ws;                        // B*N*T float4 = 16 MB
    float* TP   = (float*)(pdb + (size_t)B_ * N_ * T_);
    float* DD   = TP + B_ * N_ * L_;
    float* sumP = DD + B_ * N_ * L_;
    float* sumB = sumP + B_ * N_;

    int total = B_ * T_ * N_;
    k_transform<<<(total + 255) / 256, 256, 0, stream>>>(preds_mask, pdb);
    k_matmul<<<B_ * N_, 1024, 0, stream>>>(pdb, targets, TP, DD, sumP, sumB);
    k_final<<<B_ * L_, 128, 0, stream>>>(targets, preds_class, weight, alpha, beta,
                                         TP, DD, sumP, sumB, out);
}

// Round 2
// 83.322 us; speedup vs baseline: 1.5200x; 1.5200x over previous
//
#include <hip/hip_runtime.h>
#include <math.h>

#define B_ 2
#define T_ 4096
#define N_ 128
#define L_ 64
#define CT 64              // t-chunk per block
#define NC (T_/CT)         // 64 chunks per batch

constexpr float GAMMA_ = 0.75f;
constexpr float EPS_ = 1e-6f;

// ---------------------------------------------------------------------------
// Fused transform + partial matmul.
// Grid: B_ * NC * 2 halves = 256 blocks, 256 threads.
// Block (b, c, h): t-range [c*64, c*64+64), n-range [h*64, h*64+64), all 64 m.
//
// Phase 1: stage transformed preds (p, A-Bv) into LDS pd[n][t], targets into
//          gs[m][t]; accumulate per-n sums of p and Bv, per-m sums of tgt.
// Phase 2: register-tiled partial matmul: each thread owns 4n x 4m x {tp,dd}
//          accumulators over the 64-t chunk.  VALU-bound: 32 FMA per t-step
//          per thread vs 8 LDS read instructions.
// Outputs: Cp_tp/Cp_dd [b][n][ch][m] partials, sumPp/sumBp [b][n][ch],
//          sumTp [b][m][ch].
// ---------------------------------------------------------------------------
__global__ void __launch_bounds__(256)
k_fused(const float* __restrict__ preds, const float* __restrict__ targets,
        float* __restrict__ Cp_tp, float* __restrict__ Cp_dd,
        float* __restrict__ sumPp, float* __restrict__ sumBp,
        float* __restrict__ sumTp) {
    int bid = blockIdx.x;
    int b = bid >> 7;              // 128 blocks per batch
    int c = (bid >> 1) & (NC - 1);
    int h = bid & 1;
    int tid = threadIdx.x;

    __shared__ float2 pd[64][CT + 1];   // (p, A-Bv), [local n][t]  ~33 KB
    __shared__ float  gs[64][CT + 1];   // targets,   [m][t]        ~17 KB
    __shared__ float  redA[4][64];
    __shared__ float  redB[4][64];
    __shared__ float  redT[4][64];

    int ln = tid & 63;
    int ti = tid >> 6;             // 0..3

    // ---- phase 1a: preds chunk (64 t x 64 n), coalesced rows ----
    const float* pb = preds + ((size_t)b * T_ + (size_t)c * CT) * N_ + h * 64;
    float sp = 0.f, sb = 0.f;
#pragma unroll
    for (int i = 0; i < 16; ++i) {
        int t = 4 * i + ti;
        float x = pb[t * N_ + ln];
        float e = expf(-x);
        float p = 1.f / (1.f + e);
        float spn = log1pf(e);         // softplus(-x)
        float spp = x + spn;           // softplus(x)
        float A  = sqrtf(sqrtf(1.f - p + EPS_)) * spn;   // ^0.25
        float Bv = sqrtf(sqrtf(p + EPS_)) * spp;
        pd[ln][t] = make_float2(p, A - Bv);
        sp += p;
        sb += Bv;
    }
    redA[ti][ln] = sp;
    redB[ti][ln] = sb;

    // ---- phase 1b: targets chunk (64 t x 64 m), coalesced rows ----
    const float* tb = targets + ((size_t)b * T_ + (size_t)c * CT) * L_;
    float st = 0.f;
#pragma unroll
    for (int i = 0; i < 16; ++i) {
        int t = 4 * i + ti;
        float v = tb[t * L_ + ln];
        gs[ln][t] = v;
        st += v;
    }
    redT[ti][ln] = st;
    __syncthreads();

    // ---- per-chunk sum outputs ----
    if (tid < 64) {
        float s1 = redA[0][tid] + redA[1][tid] + redA[2][tid] + redA[3][tid];
        float s2 = redB[0][tid] + redB[1][tid] + redB[2][tid] + redB[3][tid];
        size_t o = ((size_t)b * N_ + h * 64 + tid) * NC + c;
        sumPp[o] = s1;
        sumBp[o] = s2;
    } else if (h == 0 && tid < 128) {
        int mm = tid - 64;
        float s = redT[0][mm] + redT[1][mm] + redT[2][mm] + redT[3][mm];
        sumTp[((size_t)b * L_ + mm) * NC + c] = s;
    }

    // ---- phase 2: register-tiled partial matmul ----
    int in = tid >> 4;             // n-tile 0..15 (4 n each)
    int jm = tid & 15;             // m = jm + 16*s, s=0..3 (coalesced stores)
    float atp[4][4] = {{0.f}};
    float add_[4][4] = {{0.f}};
#pragma unroll 4
    for (int t = 0; t < CT; ++t) {
        float2 pv[4];
#pragma unroll
        for (int r = 0; r < 4; ++r) pv[r] = pd[in * 4 + r][t];
        float gv[4];
#pragma unroll
        for (int s = 0; s < 4; ++s) gv[s] = gs[jm + 16 * s][t];
#pragma unroll
        for (int r = 0; r < 4; ++r)
#pragma unroll
            for (int s = 0; s < 4; ++s) {
                atp[r][s]  = fmaf(pv[r].x, gv[s], atp[r][s]);
                add_[r][s] = fmaf(pv[r].y, gv[s], add_[r][s]);
            }
    }

#pragma unroll
    for (int r = 0; r < 4; ++r) {
        int n = h * 64 + in * 4 + r;
        size_t base = (((size_t)b * N_ + n) * NC + c) * L_;
#pragma unroll
        for (int s = 0; s < 4; ++s) {
            int m = jm + 16 * s;
            Cp_tp[base + m] = atp[r][s];
            Cp_dd[base + m] = add_[r][s];
        }
    }
}

// ---------------------------------------------------------------------------
// Reduce partials over 64 chunks + finalize.
// Grid: B_*N_ = 256 blocks, 256 threads (q = tid>>6 splits chunk range).
// ---------------------------------------------------------------------------
__global__ void __launch_bounds__(256)
k_final(const float* __restrict__ preds_class, const float* __restrict__ weight,
        const float* __restrict__ alpha, const float* __restrict__ beta,
        const float* __restrict__ Cp_tp, const float* __restrict__ Cp_dd,
        const float* __restrict__ sumPp, const float* __restrict__ sumBp,
        const float* __restrict__ sumTp, float* __restrict__ out) {
    int bid = blockIdx.x;
    int b = bid >> 7;
    int n = bid & 127;
    int tid = threadIdx.x;
    int q = tid >> 6;              // 0..3, chunk-range split
    int m = tid & 63;

    __shared__ float rtp[4][64];
    __shared__ float rdd[4][64];
    __shared__ float rst[4][64];
    __shared__ float ssp, ssb;

    // tp/dd partial: chunks q*16..q*16+15, coalesced 256 B per wave per chunk
    size_t cbase = (((size_t)b * N_ + n) * NC) * L_ + m;
    float tp = 0.f, dd = 0.f;
#pragma unroll
    for (int k = 0; k < 16; ++k) {
        size_t o = cbase + (size_t)(q * 16 + k) * L_;
        tp += Cp_tp[o];
        dd += Cp_dd[o];
    }
    rtp[q][m] = tp;
    rdd[q][m] = dd;

    // sumT partial: contiguous per thread
    const float* stp_ = sumTp + ((size_t)b * L_ + m) * NC + q * 16;
    float st = 0.f;
#pragma unroll
    for (int k = 0; k < 16; ++k) st += stp_[k];
    rst[q][m] = st;

    // sumP / sumB: one full wave each, shfl reduce over 64 lanes
    if (tid < 64) {
        float v = sumPp[((size_t)b * N_ + n) * NC + tid];
        for (int o = 32; o > 0; o >>= 1) v += __shfl_xor(v, o);
        if (tid == 0) ssp = v;
    } else if (tid < 128) {
        int l = tid - 64;
        float v = sumBp[((size_t)b * N_ + n) * NC + l];
        for (int o = 32; o > 0; o >>= 1) v += __shfl_xor(v, o);
        if (l == 0) ssb = v;
    }
    __syncthreads();

    if (q == 0) {
        float tpt = rtp[0][m] + rtp[1][m] + rtp[2][m] + rtp[3][m];
        float ddt = rdd[0][m] + rdd[1][m] + rdd[2][m] + rdd[3][m];
        float stt = rst[0][m] + rst[1][m] + rst[2][m] + rst[3][m];
        float sp = ssp, sb = ssb;

        float wv = weight[m];
        float ws = wv;
        for (int o = 32; o > 0; o >>= 1) ws += __shfl_xor(ws, o);

        float a  = alpha[m];
        float bb = beta[m];

        float cost_dia = (wv / ws) * (sb + ddt) * (1.0f / (float)T_);

        float fpv = sp - tpt;
        float fnv = stt - tpt;
        float tv = (tpt + EPS_) / (tpt + a * fpv + bb * fnv + EPS_);
        float cost_dice = powf(1.f - tv + EPS_, GAMMA_);

        float cls = preds_class[b * N_ + n];
        float sig = 1.f / (1.f + expf(-cls));

        out[((size_t)b * N_ + n) * L_ + m] = 5.f * cost_dia + 5.f * cost_dice - 2.f * sig;
    }
}

extern "C" void kernel_launch(void* const* d_in, const int* in_sizes, int n_in,
                              void* d_out, int out_size, void* d_ws, size_t ws_size,
                              hipStream_t stream) {
    const float* preds_mask  = (const float*)d_in[0];   // (B,T,N)
    const float* preds_class = (const float*)d_in[1];   // (B,N,1)
    const float* targets     = (const float*)d_in[2];   // (B,T,L)
    const float* weight      = (const float*)d_in[3];   // (N,)
    const float* alpha       = (const float*)d_in[4];   // (N,)
    const float* beta        = (const float*)d_in[5];   // (N,)
    float* out = (float*)d_out;

    // workspace layout (all fp32): ~8.55 MB total
    float* Cp_tp = (float*)d_ws;                          // B*N*NC*L = 1 Mi
    float* Cp_dd = Cp_tp + (size_t)B_ * N_ * NC * L_;
    float* sumPp = Cp_dd + (size_t)B_ * N_ * NC * L_;     // B*N*NC
    float* sumBp = sumPp + (size_t)B_ * N_ * NC;
    float* sumTp = sumBp + (size_t)B_ * N_ * NC;          // B*L*NC

    k_fused<<<B_ * NC * 2, 256, 0, stream>>>(preds_mask, targets,
                                             Cp_tp, Cp_dd, sumPp, sumBp, sumTp);
    k_final<<<B_ * N_, 256, 0, stream>>>(preds_class, weight, alpha, beta,
                                         Cp_tp, Cp_dd, sumPp, sumBp, sumTp, out);
}